// Round 1
// baseline (282.438 us; speedup 1.0000x reference)
//
#include <hip/hip_runtime.h>
#include <math.h>

#define B_SZ 2
#define HH 64
#define WW 64
#define DM 192
#define NS 16
#define RR 12
#define KD 4
#define LL (HH * WW)           // 4096
#define CPROJ (RR + 2 * NS)    // 44
#define CPAD 48
#define NCH 64
#define CH (LL / NCH)          // 64
#define SCH 16                 // steps per LDS staging round

// spatial index (row-major h*W+w) that scan position t of direction k touches
__device__ __forceinline__ int spatial_idx(int k, int t) {
    if (k == 0) return t;
    if (k == 1) return ((t & 63) << 6) | (t >> 6);          // t = w*H + h -> l = h*W + w
    if (k == 2) return LL - 1 - t;
    int tp = LL - 1 - t;
    return ((tp & 63) << 6) | (tp >> 6);
}

__device__ __forceinline__ float softplus_f(float z) {
    if (z > 20.f) return z;
    return log1pf(__expf(z));
}

// ---------------- projection: x_dbl[b,k,l,c] = sum_d xs[b,k,d,l] * W[k,c,d] ----------------
__global__ __launch_bounds__(256) void proj_kernel(const float* __restrict__ x,
                                                   const float* __restrict__ xpw,
                                                   float* __restrict__ xdbl) {
    const int TL = 32;
    int blk = blockIdx.x;                    // B*K*(L/TL)
    int ltile = blk % (LL / TL);
    int bk = blk / (LL / TL);
    int k = bk % KD;
    int b = bk / KD;
    int l0 = ltile * TL;
    __shared__ float xr[TL * DM];            // 24 KiB
    for (int i = threadIdx.x; i < TL * DM; i += 256) {
        int li = i / DM, d = i - li * DM;
        int s = spatial_idx(k, l0 + li);
        xr[i] = x[((size_t)b * LL + s) * DM + d];
    }
    __syncthreads();
    const float* wk = xpw + (size_t)k * CPROJ * DM;
    for (int o = threadIdx.x; o < TL * CPROJ; o += 256) {
        int li = o / CPROJ, c = o - li * CPROJ;
        const float* wr = wk + (size_t)c * DM;
        const float* xv = xr + li * DM;
        float acc = 0.f;
#pragma unroll 8
        for (int d = 0; d < DM; ++d) acc = fmaf(xv[d], wr[d], acc);
        xdbl[((size_t)bk * LL + (l0 + li)) * CPAD + c] = acc;
    }
}

// ---------------- chunked selective scan, phases 1 (carries) and 3 (emit y) ----------------
template <int PHASE>
__global__ __launch_bounds__(192) void scan_kernel(
    const float* __restrict__ x, const float* __restrict__ xdbl,
    const float* __restrict__ dtw, const float* __restrict__ dtb,
    const float* __restrict__ Alogs, const float* __restrict__ Ds,
    float* __restrict__ carry, float* __restrict__ aprod, float* __restrict__ ybuf) {
    int blk = blockIdx.x;                 // B*K*NCH
    int chunk = blk % NCH;
    int bk = blk / NCH;
    int k = bk % KD;
    int b = bk / KD;
    int d = threadIdx.x;                  // 0..191
    int kd = k * DM + d;

    float Wdt[RR];
#pragma unroll
    for (int r = 0; r < RR; ++r) Wdt[r] = dtw[(size_t)kd * RR + r];
    float bias = dtb[kd];
    float Av[NS];
#pragma unroll
    for (int n = 0; n < NS; ++n) Av[n] = -__expf(Alogs[(size_t)kd * NS + n]);
    float Dval = Ds[kd];

    float h[NS], ap[NS];
    size_t cbase = ((size_t)(bk * NCH + chunk) * DM + d) * NS;
    if (PHASE == 1) {
#pragma unroll
        for (int n = 0; n < NS; ++n) { h[n] = 0.f; ap[n] = 1.f; }
    } else {
#pragma unroll
        for (int n = 0; n < NS; ++n) h[n] = carry[cbase + n];   // h_in written by fix_kernel
    }

    __shared__ float lds[SCH * CPAD];
    int tbase = chunk * CH;
    for (int t0 = tbase; t0 < tbase + CH; t0 += SCH) {
        __syncthreads();
        for (int i = threadIdx.x; i < SCH * CPAD; i += DM)
            lds[i] = xdbl[((size_t)bk * LL + t0) * CPAD + i];
        __syncthreads();
        for (int tt = 0; tt < SCH; ++tt) {
            const float* row = lds + tt * CPAD;
            int t = t0 + tt;
            float z = bias;
#pragma unroll
            for (int r = 0; r < RR; ++r) z = fmaf(row[r], Wdt[r], z);
            float dt = softplus_f(z);
            int s = spatial_idx(k, t);
            float xv = x[((size_t)b * LL + s) * DM + d];
            float dtx = dt * xv;
            float y = 0.f;
#pragma unroll
            for (int n = 0; n < NS; ++n) {
                float dA = __expf(dt * Av[n]);
                h[n] = fmaf(dA, h[n], dtx * row[RR + n]);
                if (PHASE == 1) ap[n] *= dA;
                else            y = fmaf(h[n], row[RR + NS + n], y);
            }
            if (PHASE == 3) {
                atomicAdd(&ybuf[((size_t)b * LL + s) * DM + d], y + Dval * xv);
            }
        }
    }
    if (PHASE == 1) {
#pragma unroll
        for (int n = 0; n < NS; ++n) { carry[cbase + n] = h[n]; aprod[cbase + n] = ap[n]; }
    }
}

// ---------------- inter-chunk sequential fixup: carry[c] <- h_in(chunk c) ----------------
__global__ __launch_bounds__(256) void fix_kernel(float* __restrict__ carry,
                                                  const float* __restrict__ aprod) {
    int idx = blockIdx.x * 256 + threadIdx.x;   // B*K*D*N = 24576
    int n = idx & (NS - 1);
    int dn = idx >> 4;
    int d = dn % DM;
    int bk = dn / DM;
    size_t base = ((size_t)bk * NCH * DM + d) * NS + n;
    const size_t stride = (size_t)DM * NS;
    float hp = 0.f;
    for (int c = 0; c < NCH; ++c) {
        size_t off = base + (size_t)c * stride;
        float P = aprod[off];
        float Cr = carry[off];
        carry[off] = hp;                 // state entering chunk c
        hp = fmaf(P, hp, Cr);
    }
}

// ---------------- LayerNorm over D=192, wave per row ----------------
__global__ __launch_bounds__(256) void ln_kernel(const float* __restrict__ ybuf,
                                                 const float* __restrict__ lnw,
                                                 const float* __restrict__ lnb,
                                                 float* __restrict__ out) {
    int row = blockIdx.x * 4 + (threadIdx.x >> 6);   // B*L rows
    int lane = threadIdx.x & 63;
    const float* yr = ybuf + (size_t)row * DM;
    float v0 = yr[lane], v1 = yr[lane + 64], v2 = yr[lane + 128];
    float s = v0 + v1 + v2;
    float sq = v0 * v0 + v1 * v1 + v2 * v2;
#pragma unroll
    for (int off = 32; off >= 1; off >>= 1) {
        s += __shfl_xor(s, off, 64);
        sq += __shfl_xor(sq, off, 64);
    }
    float mu = s * (1.f / DM);
    float var = sq * (1.f / DM) - mu * mu;
    float inv = rsqrtf(var + 1e-5f);
    float* orow = out + (size_t)row * DM;
    orow[lane]       = (v0 - mu) * inv * lnw[lane]       + lnb[lane];
    orow[lane + 64]  = (v1 - mu) * inv * lnw[lane + 64]  + lnb[lane + 64];
    orow[lane + 128] = (v2 - mu) * inv * lnw[lane + 128] + lnb[lane + 128];
}

extern "C" void kernel_launch(void* const* d_in, const int* in_sizes, int n_in,
                              void* d_out, int out_size, void* d_ws, size_t ws_size,
                              hipStream_t stream) {
    const float* x    = (const float*)d_in[0];
    const float* xpw  = (const float*)d_in[1];
    const float* dtw  = (const float*)d_in[2];
    const float* dtb  = (const float*)d_in[3];
    const float* Alog = (const float*)d_in[4];
    const float* Ds   = (const float*)d_in[5];
    const float* lnw  = (const float*)d_in[6];
    const float* lnb  = (const float*)d_in[7];
    float* out = (float*)d_out;

    // workspace: 4 buffers x 1,572,864 floats = 25.2 MB total
    const size_t SEG = (size_t)B_SZ * KD * LL * CPAD;   // 1,572,864 (== B*K*NCH*D*N == B*L*D)
    float* ws    = (float*)d_ws;
    float* xdbl  = ws;
    float* carry = xdbl + SEG;
    float* aprod = carry + SEG;
    float* ybuf  = aprod + SEG;

    hipMemsetAsync(ybuf, 0, (size_t)B_SZ * LL * DM * sizeof(float), stream);
    proj_kernel<<<B_SZ * KD * (LL / 32), 256, 0, stream>>>(x, xpw, xdbl);
    scan_kernel<1><<<B_SZ * KD * NCH, DM, 0, stream>>>(x, xdbl, dtw, dtb, Alog, Ds,
                                                       carry, aprod, ybuf);
    fix_kernel<<<(B_SZ * KD * DM * NS) / 256, 256, 0, stream>>>(carry, aprod);
    scan_kernel<3><<<B_SZ * KD * NCH, DM, 0, stream>>>(x, xdbl, dtw, dtb, Alog, Ds,
                                                       carry, aprod, ybuf);
    ln_kernel<<<(B_SZ * LL) / 4, 256, 0, stream>>>(ybuf, lnw, lnb, out);
}

// Round 2
// 100.887 us; speedup vs baseline: 2.7995x; 2.7995x over previous
//
#include <hip/hip_runtime.h>
#include <math.h>

#define B_SZ 2
#define HH 64
#define WW 64
#define DM 192
#define NS 16
#define RR 12
#define KD 4
#define LL (HH * WW)           // 4096
#define CPROJ (RR + 2 * NS)    // 44
#define CPAD 48
#define SCH 16                 // steps per LDS staging round in scan
#define TLP 64                 // l-tile per proj block
#define LOG2E 1.44269504088896340736f

// spatial index (row-major h*W+w) that scan position t of direction k touches
__device__ __forceinline__ int spatial_idx(int k, int t) {
    if (k == 0) return t;
    if (k == 1) return ((t & 63) << 6) | (t >> 6);          // t = w*H + h -> l = h*W + w
    if (k == 2) return LL - 1 - t;
    int tp = LL - 1 - t;
    return ((tp & 63) << 6) | (tp >> 6);
}

// ---------------- projection: xdbl[bk][l][c] = sum_d xs[b,k,d,l] * W[k,c,d] ----------------
// lane = l within 64-wide tile; wave owns 11 of 44 channels; weights via scalar loads.
__global__ __launch_bounds__(256) void proj_kernel(const float* __restrict__ x,
                                                   const float* __restrict__ xpw,
                                                   float* __restrict__ xdbl) {
    int blk = blockIdx.x;                    // B*K*(L/TLP) = 512
    int ltile = blk % (LL / TLP);
    int bk = blk / (LL / TLP);
    int k = bk & 3;
    int b = bk >> 2;
    int l0 = ltile * TLP;

    __shared__ float xt[DM * (TLP + 1)];     // transposed tile, stride 65 -> conflict-free reads

    // load: 4 threads per row, each 48 consecutive d as 12 float4s
    {
        int li = threadIdx.x >> 2;
        int d0 = (threadIdx.x & 3) * 48;
        int s = spatial_idx(k, l0 + li);
        const float4* xr = (const float4*)(x + ((size_t)b * LL + s) * DM + d0);
#pragma unroll
        for (int q = 0; q < 12; ++q) {
            float4 v = xr[q];
            int d = d0 + q * 4;
            xt[(d + 0) * (TLP + 1) + li] = v.x;
            xt[(d + 1) * (TLP + 1) + li] = v.y;
            xt[(d + 2) * (TLP + 1) + li] = v.z;
            xt[(d + 3) * (TLP + 1) + li] = v.w;
        }
    }
    __syncthreads();

    int lane = threadIdx.x & 63;
    int wv = threadIdx.x >> 6;               // 0..3
    int c0 = __builtin_amdgcn_readfirstlane(wv * 11);
    const float* wk = xpw + (size_t)k * CPROJ * DM;

    float acc[11];
#pragma unroll
    for (int ci = 0; ci < 11; ++ci) acc[ci] = 0.f;

    for (int d = 0; d < DM; ++d) {
        float xv = xt[d * (TLP + 1) + lane];
#pragma unroll
        for (int ci = 0; ci < 11; ++ci)
            acc[ci] = fmaf(xv, wk[(size_t)(c0 + ci) * DM + d], acc[ci]);
    }
    float* orow = xdbl + ((size_t)bk * LL + l0 + lane) * CPAD;
#pragma unroll
    for (int ci = 0; ci < 11; ++ci) orow[c0 + ci] = acc[ci];
}

// ---------------- chunked selective scan, phases 1 (carries) and 3 (emit y) ----------------
template <int PHASE, int NCHT>
__global__ __launch_bounds__(192) void scan_kernel(
    const float* __restrict__ x, const float* __restrict__ xdbl,
    const float* __restrict__ dtw, const float* __restrict__ dtb,
    const float* __restrict__ Alogs, const float* __restrict__ Ds,
    float* __restrict__ carry, float* __restrict__ aprod, float* __restrict__ ybuf) {
    const int CHT = LL / NCHT;
    int blk = blockIdx.x;                 // B*K*NCHT
    int chunk = blk % NCHT;
    int bk = blk / NCHT;
    int k = bk & 3;
    int b = bk >> 2;
    int d = threadIdx.x;                  // 0..191
    int kd = k * DM + d;

    float Wdt[RR];
#pragma unroll
    for (int r = 0; r < RR; ++r) Wdt[r] = dtw[(size_t)kd * RR + r];
    float bias = dtb[kd];
    float Avl2[NS];
#pragma unroll
    for (int n = 0; n < NS; ++n) Avl2[n] = -__expf(Alogs[(size_t)kd * NS + n]) * LOG2E;
    float Dval = Ds[kd];

    // structure fast path: Av[n] == (n+1)*Av[0]  (holds for A_log_init; verified at runtime)
    bool pws = true;
#pragma unroll
    for (int n = 0; n < NS; ++n)
        pws = pws && (fabsf(Avl2[n] - (float)(n + 1) * Avl2[0]) <= 1e-5f * fabsf(Avl2[n]) + 1e-30f);
    const bool pw = (__all(pws ? 1 : 0) != 0);

    float h[NS];
    float dtsum = 0.f;
    size_t cbase = ((size_t)(bk * NCHT + chunk) * DM + d) * NS;
    if (PHASE == 1) {
#pragma unroll
        for (int n = 0; n < NS; ++n) h[n] = 0.f;
    } else {
#pragma unroll
        for (int n = 0; n < NS; ++n) h[n] = carry[cbase + n];   // h_in written by fix_kernel
    }

    __shared__ float lds[SCH * CPAD];
    int tbase = chunk * CHT;
    for (int t0 = tbase; t0 < tbase + CHT; t0 += SCH) {
        __syncthreads();
        for (int i = threadIdx.x; i < SCH * CPAD; i += DM)
            lds[i] = xdbl[((size_t)bk * LL + t0) * CPAD + i];
        __syncthreads();
        for (int tt = 0; tt < SCH; ++tt) {
            const float* row = lds + tt * CPAD;
            int t = t0 + tt;
            float z = bias;
#pragma unroll
            for (int r = 0; r < RR; ++r) z = fmaf(row[r], Wdt[r], z);
            float dt = (z > 15.f) ? z : __logf(1.f + __expf(z));
            int s = spatial_idx(k, t);
            float xv = x[((size_t)b * LL + s) * DM + d];
            float dtx = dt * xv;

            float dA[NS];
            if (pw) {
                float e1 = exp2f(dt * Avl2[0]);
                dA[0] = e1;
                dA[1] = e1 * e1;
                dA[2] = dA[1] * e1;
                dA[3] = dA[1] * dA[1];
                dA[4] = dA[3] * e1;
                dA[5] = dA[3] * dA[1];
                dA[6] = dA[3] * dA[2];
                dA[7] = dA[3] * dA[3];
                dA[8] = dA[7] * e1;
                dA[9] = dA[7] * dA[1];
                dA[10] = dA[7] * dA[2];
                dA[11] = dA[7] * dA[3];
                dA[12] = dA[7] * dA[4];
                dA[13] = dA[7] * dA[5];
                dA[14] = dA[7] * dA[6];
                dA[15] = dA[7] * dA[7];
            } else {
#pragma unroll
                for (int n = 0; n < NS; ++n) dA[n] = exp2f(dt * Avl2[n]);
            }

            float y = 0.f;
#pragma unroll
            for (int n = 0; n < NS; ++n) {
                h[n] = fmaf(dA[n], h[n], dtx * row[RR + n]);
                if (PHASE == 3) y = fmaf(h[n], row[RR + NS + n], y);
            }
            if (PHASE == 1) dtsum += dt;
            if (PHASE == 3) {
                atomicAdd(&ybuf[((size_t)b * LL + s) * DM + d], y + Dval * xv);
            }
        }
    }
    if (PHASE == 1) {
#pragma unroll
        for (int n = 0; n < NS; ++n) {
            carry[cbase + n] = h[n];
            aprod[cbase + n] = exp2f(dtsum * Avl2[n]);   // prod of dA == exp(Av * sum dt)
        }
    }
}

// ---------------- inter-chunk sequential fixup: carry[c] <- h_in(chunk c) ----------------
template <int NCHT>
__global__ __launch_bounds__(256) void fix_kernel(float* __restrict__ carry,
                                                  const float* __restrict__ aprod) {
    int idx = blockIdx.x * 256 + threadIdx.x;   // B*K*D*N = 24576
    int n = idx & (NS - 1);
    int dn = idx >> 4;
    int d = dn % DM;
    int bk = dn / DM;
    size_t base = ((size_t)bk * NCHT * DM + d) * NS + n;
    const size_t stride = (size_t)DM * NS;
    float hp = 0.f;
    for (int c = 0; c < NCHT; ++c) {
        size_t off = base + (size_t)c * stride;
        float P = aprod[off];
        float Cr = carry[off];
        carry[off] = hp;                 // state entering chunk c
        hp = fmaf(P, hp, Cr);
    }
}

// ---------------- LayerNorm over D=192, wave per row ----------------
__global__ __launch_bounds__(256) void ln_kernel(const float* __restrict__ ybuf,
                                                 const float* __restrict__ lnw,
                                                 const float* __restrict__ lnb,
                                                 float* __restrict__ out) {
    int row = blockIdx.x * 4 + (threadIdx.x >> 6);   // B*L rows
    int lane = threadIdx.x & 63;
    const float* yr = ybuf + (size_t)row * DM;
    float v0 = yr[lane], v1 = yr[lane + 64], v2 = yr[lane + 128];
    float s = v0 + v1 + v2;
    float sq = v0 * v0 + v1 * v1 + v2 * v2;
#pragma unroll
    for (int off = 32; off >= 1; off >>= 1) {
        s += __shfl_xor(s, off, 64);
        sq += __shfl_xor(sq, off, 64);
    }
    float mu = s * (1.f / DM);
    float var = sq * (1.f / DM) - mu * mu;
    float inv = rsqrtf(var + 1e-5f);
    float* orow = out + (size_t)row * DM;
    orow[lane]       = (v0 - mu) * inv * lnw[lane]       + lnb[lane];
    orow[lane + 64]  = (v1 - mu) * inv * lnw[lane + 64]  + lnb[lane + 64];
    orow[lane + 128] = (v2 - mu) * inv * lnw[lane + 128] + lnb[lane + 128];
}

extern "C" void kernel_launch(void* const* d_in, const int* in_sizes, int n_in,
                              void* d_out, int out_size, void* d_ws, size_t ws_size,
                              hipStream_t stream) {
    const float* x    = (const float*)d_in[0];
    const float* xpw  = (const float*)d_in[1];
    const float* dtw  = (const float*)d_in[2];
    const float* dtb  = (const float*)d_in[3];
    const float* Alog = (const float*)d_in[4];
    const float* Ds   = (const float*)d_in[5];
    const float* lnw  = (const float*)d_in[6];
    const float* lnb  = (const float*)d_in[7];
    float* out = (float*)d_out;

    const size_t F_XD   = (size_t)B_SZ * KD * LL * CPAD;        // 1,572,864 floats
    const size_t F_C64  = (size_t)B_SZ * KD * 64 * DM * NS;     // 1,572,864 floats
    const size_t F_C128 = 2 * F_C64;
    const size_t F_YB   = (size_t)B_SZ * LL * DM;               // 1,572,864 floats

    float* ws   = (float*)d_ws;
    float* xdbl = ws;

    proj_kernel<<<B_SZ * KD * (LL / TLP), 256, 0, stream>>>(x, xpw, xdbl);

    if (ws_size >= (F_XD + 2 * F_C128) * sizeof(float)) {
        // high-occupancy layout (31.5 MB): ybuf aliases aprod (dead after fix_kernel)
        float* carry = xdbl + F_XD;
        float* aprod = carry + F_C128;
        float* ybuf  = aprod;
        scan_kernel<1, 128><<<B_SZ * KD * 128, DM, 0, stream>>>(x, xdbl, dtw, dtb, Alog, Ds,
                                                                carry, aprod, ybuf);
        fix_kernel<128><<<(B_SZ * KD * DM * NS) / 256, 256, 0, stream>>>(carry, aprod);
        hipMemsetAsync(ybuf, 0, F_YB * sizeof(float), stream);
        scan_kernel<3, 128><<<B_SZ * KD * 128, DM, 0, stream>>>(x, xdbl, dtw, dtb, Alog, Ds,
                                                                carry, aprod, ybuf);
        ln_kernel<<<(B_SZ * LL) / 4, 256, 0, stream>>>(ybuf, lnw, lnb, out);
    } else {
        // conservative 25.2 MB layout (known to fit)
        float* carry = xdbl + F_XD;
        float* aprod = carry + F_C64;
        float* ybuf  = aprod + F_C64;
        scan_kernel<1, 64><<<B_SZ * KD * 64, DM, 0, stream>>>(x, xdbl, dtw, dtb, Alog, Ds,
                                                              carry, aprod, ybuf);
        fix_kernel<64><<<(B_SZ * KD * DM * NS) / 256, 256, 0, stream>>>(carry, aprod);
        hipMemsetAsync(ybuf, 0, F_YB * sizeof(float), stream);
        scan_kernel<3, 64><<<B_SZ * KD * 64, DM, 0, stream>>>(x, xdbl, dtw, dtb, Alog, Ds,
                                                              carry, aprod, ybuf);
        ln_kernel<<<(B_SZ * LL) / 4, 256, 0, stream>>>(ybuf, lnw, lnb, out);
    }
}

// Round 3
// 94.450 us; speedup vs baseline: 2.9903x; 1.0681x over previous
//
#include <hip/hip_runtime.h>
#include <math.h>

#define B_SZ 2
#define HH 64
#define WW 64
#define DM 192
#define NS 16
#define RR 12
#define KD 4
#define LL (HH * WW)           // 4096
#define CPROJ (RR + 2 * NS)    // 44
#define CPAD 48
#define SCH 16                 // steps per LDS staging round in scan
#define TLP 64                 // l-tile per proj block
#define LOG2E 1.44269504088896340736f
#define LN2F 0.69314718055994530942f

// spatial index (row-major h*W+w) that scan position t of direction k touches
__device__ __forceinline__ int spatial_idx(int k, int t) {
    if (k == 0) return t;
    if (k == 1) return ((t & 63) << 6) | (t >> 6);          // t = w*H + h -> l = h*W + w
    if (k == 2) return LL - 1 - t;
    int tp = LL - 1 - t;
    return ((tp & 63) << 6) | (tp >> 6);
}

// ---------------- projection: xdbl[bk][l][c] = sum_d xs[b,k,d,l] * W[k,c,d] ----------------
__global__ __launch_bounds__(256) void proj_kernel(const float* __restrict__ x,
                                                   const float* __restrict__ xpw,
                                                   float* __restrict__ xdbl) {
    int blk = blockIdx.x;                    // B*K*(L/TLP) = 512
    int ltile = blk % (LL / TLP);
    int bk = blk / (LL / TLP);
    int k = bk & 3;
    int b = bk >> 2;
    int l0 = ltile * TLP;

    __shared__ float xt[DM * (TLP + 1)];     // transposed tile, stride 65 -> conflict-free reads

    {
        int li = threadIdx.x >> 2;
        int d0 = (threadIdx.x & 3) * 48;
        int s = spatial_idx(k, l0 + li);
        const float4* xr = (const float4*)(x + ((size_t)b * LL + s) * DM + d0);
#pragma unroll
        for (int q = 0; q < 12; ++q) {
            float4 v = xr[q];
            int d = d0 + q * 4;
            xt[(d + 0) * (TLP + 1) + li] = v.x;
            xt[(d + 1) * (TLP + 1) + li] = v.y;
            xt[(d + 2) * (TLP + 1) + li] = v.z;
            xt[(d + 3) * (TLP + 1) + li] = v.w;
        }
    }
    __syncthreads();

    int lane = threadIdx.x & 63;
    int wv = threadIdx.x >> 6;               // 0..3
    int c0 = __builtin_amdgcn_readfirstlane(wv * 11);
    const float* wk = xpw + (size_t)k * CPROJ * DM;

    float acc[11];
#pragma unroll
    for (int ci = 0; ci < 11; ++ci) acc[ci] = 0.f;

    for (int d = 0; d < DM; ++d) {
        float xv = xt[d * (TLP + 1) + lane];
#pragma unroll
        for (int ci = 0; ci < 11; ++ci)
            acc[ci] = fmaf(xv, wk[(size_t)(c0 + ci) * DM + d], acc[ci]);
    }
    float* orow = xdbl + ((size_t)bk * LL + l0 + lane) * CPAD;
#pragma unroll
    for (int ci = 0; ci < 11; ++ci) orow[c0 + ci] = acc[ci];
}

// ---------------- chunked selective scan, phases 1 (carries) and 3 (emit y) ----------------
// ATOMIC=0: phase-3 stores per-direction into ybuf (4 separate B*L*D buffers, no zeroing).
// ATOMIC=1: phase-3 atomically accumulates into one pre-zeroed B*L*D buffer (fallback).
template <int PHASE, int NCHT, int ATOMIC>
__global__ __launch_bounds__(192) void scan_kernel(
    const float* __restrict__ x, const float* __restrict__ xdbl,
    const float* __restrict__ dtw, const float* __restrict__ dtb,
    const float* __restrict__ Alogs, const float* __restrict__ Ds,
    float* __restrict__ carry, float* __restrict__ aprod, float* __restrict__ ybuf) {
    const int CHT = LL / NCHT;
    int blk = blockIdx.x;                 // B*K*NCHT
    int chunk = blk % NCHT;
    int bk = blk / NCHT;
    int k = bk & 3;
    int b = bk >> 2;
    int d = threadIdx.x;                  // 0..191
    int kd = k * DM + d;

    float Wdt[RR];
#pragma unroll
    for (int r = 0; r < RR; ++r) Wdt[r] = dtw[(size_t)kd * RR + r];
    float bias = dtb[kd];
    float Avl2[NS];
#pragma unroll
    for (int n = 0; n < NS; ++n) Avl2[n] = -__expf(Alogs[(size_t)kd * NS + n]) * LOG2E;
    float Dval = Ds[kd];

    // structure fast path: Av[n] == (n+1)*Av[0]  (holds for A_log_init; verified at runtime)
    bool pws = true;
#pragma unroll
    for (int n = 0; n < NS; ++n)
        pws = pws && (fabsf(Avl2[n] - (float)(n + 1) * Avl2[0]) <= 1e-5f * fabsf(Avl2[n]) + 1e-30f);
    const bool pw = (__all(pws ? 1 : 0) != 0);

    float h[NS];
    float dtsum = 0.f;
    size_t cbase = ((size_t)(bk * NCHT + chunk) * DM + d) * NS;
    if (PHASE == 1) {
#pragma unroll
        for (int n = 0; n < NS; ++n) h[n] = 0.f;
    } else {
#pragma unroll
        for (int n = 0; n < NS; ++n) h[n] = carry[cbase + n];   // h_in written by fix_kernel
    }

    __shared__ float lds[SCH * CPAD];
    int tbase = chunk * CHT;
    for (int t0 = tbase; t0 < tbase + CHT; t0 += SCH) {
        __syncthreads();
        for (int i = threadIdx.x; i < SCH * CPAD; i += DM)
            lds[i] = xdbl[((size_t)bk * LL + t0) * CPAD + i];
        __syncthreads();
        for (int tt = 0; tt < SCH; ++tt) {
            const float* row = lds + tt * CPAD;
            int t = t0 + tt;
            float z = bias;
#pragma unroll
            for (int r = 0; r < RR; ++r) z = fmaf(row[r], Wdt[r], z);
            // softplus: log(1+e^z) = log2(1+2^(z*log2e)) * ln2
            float dt = (z > 15.f) ? z : __log2f(1.f + exp2f(z * LOG2E)) * LN2F;
            int s = spatial_idx(k, t);
            float xv = x[((size_t)b * LL + s) * DM + d];
            float dtx = dt * xv;

            float dA[NS];
            if (pw) {
                float e1 = exp2f(dt * Avl2[0]);
                dA[0] = e1;
                dA[1] = e1 * e1;
                dA[2] = dA[1] * e1;
                dA[3] = dA[1] * dA[1];
                dA[4] = dA[3] * e1;
                dA[5] = dA[3] * dA[1];
                dA[6] = dA[3] * dA[2];
                dA[7] = dA[3] * dA[3];
                dA[8] = dA[7] * e1;
                dA[9] = dA[7] * dA[1];
                dA[10] = dA[7] * dA[2];
                dA[11] = dA[7] * dA[3];
                dA[12] = dA[7] * dA[4];
                dA[13] = dA[7] * dA[5];
                dA[14] = dA[7] * dA[6];
                dA[15] = dA[7] * dA[7];
            } else {
#pragma unroll
                for (int n = 0; n < NS; ++n) dA[n] = exp2f(dt * Avl2[n]);
            }

            float y = 0.f;
#pragma unroll
            for (int n = 0; n < NS; ++n) {
                h[n] = fmaf(dA[n], h[n], dtx * row[RR + n]);
                if (PHASE == 3) y = fmaf(h[n], row[RR + NS + n], y);
            }
            if (PHASE == 1) dtsum += dt;
            if (PHASE == 3) {
                float val = y + Dval * xv;
                size_t oidx = ((size_t)b * LL + s) * DM + d;
                if (ATOMIC) atomicAdd(&ybuf[oidx], val);
                else        ybuf[(size_t)k * (B_SZ * LL * DM) + oidx] = val;
            }
        }
    }
    if (PHASE == 1) {
#pragma unroll
        for (int n = 0; n < NS; ++n) {
            carry[cbase + n] = h[n];
            aprod[cbase + n] = exp2f(dtsum * Avl2[n]);   // prod of dA == exp(Av * sum dt)
        }
    }
}

// ---------------- inter-chunk sequential fixup: carry[c] <- h_in(chunk c) ----------------
template <int NCHT>
__global__ __launch_bounds__(256) void fix_kernel(float* __restrict__ carry,
                                                  const float* __restrict__ aprod) {
    int idx = blockIdx.x * 256 + threadIdx.x;   // B*K*D*N = 24576
    int n = idx & (NS - 1);
    int dn = idx >> 4;
    int d = dn % DM;
    int bk = dn / DM;
    size_t base = ((size_t)bk * NCHT * DM + d) * NS + n;
    const size_t stride = (size_t)DM * NS;
    float hp = 0.f;
    for (int c = 0; c < NCHT; ++c) {
        size_t off = base + (size_t)c * stride;
        float P = aprod[off];
        float Cr = carry[off];
        carry[off] = hp;                 // state entering chunk c
        hp = fmaf(P, hp, Cr);
    }
}

// ---------------- LayerNorm over D=192 with 4-direction merge, wave per row ----------------
template <int NB>
__global__ __launch_bounds__(256) void ln_kernel(const float* __restrict__ ybuf,
                                                 const float* __restrict__ lnw,
                                                 const float* __restrict__ lnb,
                                                 float* __restrict__ out) {
    const size_t SEG = (size_t)B_SZ * LL * DM;
    int row = blockIdx.x * 4 + (threadIdx.x >> 6);   // B*L rows
    int lane = threadIdx.x & 63;
    const float* yr = ybuf + (size_t)row * DM;
    float v0 = 0.f, v1 = 0.f, v2 = 0.f;
#pragma unroll
    for (int kq = 0; kq < NB; ++kq) {
        const float* p = yr + kq * SEG;
        v0 += p[lane];
        v1 += p[lane + 64];
        v2 += p[lane + 128];
    }
    float s = v0 + v1 + v2;
    float sq = v0 * v0 + v1 * v1 + v2 * v2;
#pragma unroll
    for (int off = 32; off >= 1; off >>= 1) {
        s += __shfl_xor(s, off, 64);
        sq += __shfl_xor(sq, off, 64);
    }
    float mu = s * (1.f / DM);
    float var = sq * (1.f / DM) - mu * mu;
    float inv = rsqrtf(var + 1e-5f);
    float* orow = out + (size_t)row * DM;
    orow[lane]       = (v0 - mu) * inv * lnw[lane]       + lnb[lane];
    orow[lane + 64]  = (v1 - mu) * inv * lnw[lane + 64]  + lnb[lane + 64];
    orow[lane + 128] = (v2 - mu) * inv * lnw[lane + 128] + lnb[lane + 128];
}

// grid-stride float4 zero (replacement for slow rocclr fill; fallback path only)
__global__ __launch_bounds__(256) void zero_kernel(float4* __restrict__ p, int n4) {
    for (int i = blockIdx.x * 256 + threadIdx.x; i < n4; i += gridDim.x * 256)
        p[i] = make_float4(0.f, 0.f, 0.f, 0.f);
}

extern "C" void kernel_launch(void* const* d_in, const int* in_sizes, int n_in,
                              void* d_out, int out_size, void* d_ws, size_t ws_size,
                              hipStream_t stream) {
    const float* x    = (const float*)d_in[0];
    const float* xpw  = (const float*)d_in[1];
    const float* dtw  = (const float*)d_in[2];
    const float* dtb  = (const float*)d_in[3];
    const float* Alog = (const float*)d_in[4];
    const float* Ds   = (const float*)d_in[5];
    const float* lnw  = (const float*)d_in[6];
    const float* lnb  = (const float*)d_in[7];
    float* out = (float*)d_out;

    const size_t F_XD   = (size_t)B_SZ * KD * LL * CPAD;        // 1,572,864 floats
    const size_t F_C64  = (size_t)B_SZ * KD * 64 * DM * NS;     // 1,572,864 floats
    const size_t F_C128 = 2 * F_C64;
    const size_t F_YB   = (size_t)B_SZ * LL * DM;               // 1,572,864 floats

    float* ws   = (float*)d_ws;
    float* xdbl = ws;

    proj_kernel<<<B_SZ * KD * (LL / TLP), 256, 0, stream>>>(x, xpw, xdbl);

    if (ws_size >= (F_XD + 2 * F_C128 + 4 * F_YB) * sizeof(float)) {
        // primary layout (56.7 MB): per-direction outputs, no atomics, no zeroing
        float* carry = xdbl + F_XD;
        float* aprod = carry + F_C128;
        float* ybuf4 = aprod + F_C128;
        scan_kernel<1, 128, 0><<<B_SZ * KD * 128, DM, 0, stream>>>(x, xdbl, dtw, dtb, Alog, Ds,
                                                                   carry, aprod, ybuf4);
        fix_kernel<128><<<(B_SZ * KD * DM * NS) / 256, 256, 0, stream>>>(carry, aprod);
        scan_kernel<3, 128, 0><<<B_SZ * KD * 128, DM, 0, stream>>>(x, xdbl, dtw, dtb, Alog, Ds,
                                                                   carry, aprod, ybuf4);
        ln_kernel<4><<<(B_SZ * LL) / 4, 256, 0, stream>>>(ybuf4, lnw, lnb, out);
    } else {
        // conservative 31.5 MB layout: atomic merge into one buffer, custom zero kernel
        float* carry = xdbl + F_XD;
        float* aprod = carry + F_C128;
        float* ybuf  = aprod;   // aliases aprod (dead after fix_kernel)
        scan_kernel<1, 128, 1><<<B_SZ * KD * 128, DM, 0, stream>>>(x, xdbl, dtw, dtb, Alog, Ds,
                                                                   carry, aprod, ybuf);
        fix_kernel<128><<<(B_SZ * KD * DM * NS) / 256, 256, 0, stream>>>(carry, aprod);
        zero_kernel<<<1024, 256, 0, stream>>>((float4*)ybuf, (int)(F_YB / 4));
        scan_kernel<3, 128, 1><<<B_SZ * KD * 128, DM, 0, stream>>>(x, xdbl, dtw, dtb, Alog, Ds,
                                                                   carry, aprod, ybuf);
        ln_kernel<1><<<(B_SZ * LL) / 4, 256, 0, stream>>>(ybuf, lnw, lnb, out);
    }
}